// Round 13
// baseline (1058.994 us; speedup 1.0000x reference)
//
#include <hip/hip_runtime.h>

#ifndef M_PI
#define M_PI 3.14159265358979323846
#endif

#define HH 512
#define WW 512
#define NBT 16
#define NH 5
#define NW 5
#define NR 3
#define NS 3
#define NCOMBO (NH * NW * NR * NS)  // 225

struct BlockParams {
  float Ax, Bx, Cx, Ay, By, Cy;
  int ch, cw, y1, x1;
};

// load float at byte offset from uniform base -> global_load saddr + voffset
__device__ __forceinline__ float ldg_off(const float* base, uint32_t byteOff) {
  return *reinterpret_cast<const float*>(reinterpret_cast<const char*>(base) + byteOff);
}
// 8-byte corner-pair load (global_load_dwordx2; CDNA handles 4B-aligned case)
__device__ __forceinline__ float2 ldg2_off(const float* base, uint32_t byteOff) {
  return *reinterpret_cast<const float2*>(reinterpret_cast<const char*>(base) + byteOff);
}

// interval of t such that lo <= A*t + C <= hi
__device__ __forceinline__ void interval_1d(float A, float C, float lo, float hi,
                                            float& l, float& u) {
  if (fabsf(A) > 1e-7f) {
    float a = (lo - C) / A;
    float b = (hi - C) / A;
    l = fminf(a, b);
    u = fmaxf(a, b);
  } else {
    bool in = (C >= lo && C <= hi);
    l = in ? -1e9f : 1e9f;
    u = in ? 1e9f : -1e9f;
  }
}

__device__ __forceinline__ void setup_params(BlockParams& bp, int combo,
                                             const float* shv, const float* swv,
                                             const float* rvv, const float* scv) {
  // ---- crop sizes (mirrors _crop_sizes; fp64 for exact int truncation) ----
  double max_ash = 0.0, max_asw = 0.0, max_r = -1e300, max_s = -1e300;
  for (int i = 0; i < NH; ++i) max_ash = fmax(max_ash, fabs((double)shv[i]));
  for (int i = 0; i < NW; ++i) max_asw = fmax(max_asw, fabs((double)swv[i]));
  for (int i = 0; i < NR; ++i) {
    float rf = rvv[i] * (float)(M_PI / 180.0);  // fp32 like reference
    max_r = fmax(max_r, (double)rf);
  }
  for (int i = 0; i < NS; ++i) max_s = fmax(max_s, (double)scv[i]);
  double t = fabs(tan(max_r));
  int ch = (int)((double)HH - (2.0 * (max_ash + 0.5 * HH * t) * max_s + 10.0));
  int cw = (int)((double)WW - (2.0 * (max_asw + 0.5 * WW * t) * max_s + 10.0));
  bp.ch = ch; bp.cw = cw;
  bp.y1 = (HH - ch) / 2; bp.x1 = (WW - cw) / 2;

  // ---- affine: ix = Ax*wf + Bx*hf + Cx, iy = Ay*wf + By*hf + Cy ----
  int ihh = combo / (NW * NR * NS);
  int iww = (combo / (NR * NS)) % NW;
  int irr = (combo / NS) % NR;
  int iss = combo % NS;
  double s_h = (double)shv[ihh];
  double s_w = (double)swv[iww];
  float rotf = rvv[irr] * (float)(M_PI / 180.0);
  double rot = (double)rotf;
  double scl = (double)scv[iss];
  double cs = cos(rot), sn = sin(rot);
  double cWd = (WW - 1) * 0.5, cHd = (HH - 1) * 0.5;
  double kx = ((double)WW / (WW - 1)) / scl;
  double ky = ((double)HH / (HH - 1)) / scl;
  bp.Ax = (float)(cs * kx);
  bp.Bx = (float)(sn * kx);
  bp.Cx = (float)(kx * (cs * (s_w - cWd) + sn * (s_h - cHd)) + cWd);
  bp.Ay = (float)(-sn * ky);
  bp.By = (float)(cs * ky);
  bp.Cy = (float)(ky * (-sn * (s_w - cWd) + cs * (s_h - cHd)) + cHd);
}

// One block per (combo, image). 512 threads; thread = one crop column
// marching down crop rows. Fast/slow h-split analytic + wave-uniform.
// Fast path: 3 memory insts/px (2x dwordx2 corner pairs + 1 ref dword) —
// same L2 request rate as the r4 DPP version (keeps the marginal per-XCD
// L2 residency intact) but branchless and ~20% fewer VALU ops.
__global__ __launch_bounds__(512)
void sad_kernel(const float* __restrict__ img_all,
                const float* __restrict__ ref_all,
                const float* __restrict__ shv, const float* __restrict__ swv,
                const float* __restrict__ rvv, const float* __restrict__ scv,
                float* __restrict__ sad_out) {
  __shared__ BlockParams bp;
  __shared__ double wsum[8];
  const int combo = blockIdx.x;
  const int bt = blockIdx.y;

  if (threadIdx.x == 0) setup_params(bp, combo, shv, swv, rvv, scv);
  __syncthreads();

  const int ch = bp.ch, cw = bp.cw, y1 = bp.y1, x1 = bp.x1;
  const float Ax = bp.Ax, Bx = bp.Bx, Cx = bp.Cx;
  const float Ay = bp.Ay, By = bp.By, Cy = bp.Cy;
  const float* __restrict__ img = img_all + (size_t)bt * (HH * WW);
  const float* __restrict__ ref = ref_all + (size_t)bt * (HH * WW);
  const int tid = threadIdx.x;

  const int wEff = (tid < cw) ? tid : (cw - 1);
  const float wfc = (float)(x1 + wEff);
  const float colx = fmaf(Ax, wfc, Cx);
  const float coly = fmaf(Ay, wfc, Cy);

  // fast-valid h interval: ix,iy in [0.01, 510.98] -> no masks, no clamps
  float lx, ux, ly, uy;
  interval_1d(Bx, colx, 0.01f, 510.98f, lx, ux);
  interval_1d(By, coly, 0.01f, 510.98f, ly, uy);
  float hl = fmaxf(lx, ly);
  float hu = fminf(ux, uy);
  hl = fmaxf(fminf(hl, 2000.0f), -2000.0f);
  hu = fmaxf(fminf(hu, 2000.0f), -2000.0f);
  int lo = (int)ceilf(hl) - y1;
  int hi = (int)floorf(hu) - y1 + 1;
  lo = min(max(lo, 0), ch);
  hi = min(max(hi, lo), ch);
  // wave-uniform intersection -> scalar loop bounds
  for (int off = 32; off; off >>= 1) {
    lo = max(lo, __shfl_xor(lo, off));
    hi = min(hi, __shfl_xor(hi, off));
  }
  hi = max(hi, lo);
  lo = __builtin_amdgcn_readfirstlane(lo);
  hi = __builtin_amdgcn_readfirstlane(hi);

  float acc0 = 0.0f, acc1 = 0.0f;
  float hf = (float)y1;
  uint32_t refoffB = (uint32_t)(y1 * WW + x1 + wEff) << 2;  // byte offset

#define SLOW_PX do { \
    float ix = fmaf(Bx, hf, colx); \
    float iy = fmaf(By, hf, coly); \
    float x0f = floorf(ix), y0f = floorf(iy); \
    float x1f = x0f + 1.0f, y1f = y0f + 1.0f; \
    float wx1 = ix - x0f, wy1 = iy - y0f; \
    float wx0 = 1.0f - wx1, wy0 = 1.0f - wy1; \
    float wx0m = (x0f >= 0.0f && x0f <= 511.0f) ? wx0 : 0.0f; \
    float wx1m = (x1f >= 0.0f && x1f <= 511.0f) ? wx1 : 0.0f; \
    float wy0m = (y0f >= 0.0f && y0f <= 511.0f) ? wy0 : 0.0f; \
    float wy1m = (y1f >= 0.0f && y1f <= 511.0f) ? wy1 : 0.0f; \
    uint32_t xc0 = (uint32_t)(int)fminf(fmaxf(x0f, 0.0f), 511.0f); \
    uint32_t xc1 = (uint32_t)(int)fminf(fmaxf(x1f, 0.0f), 511.0f); \
    uint32_t yc0 = (uint32_t)(int)fminf(fmaxf(y0f, 0.0f), 511.0f); \
    uint32_t yc1 = (uint32_t)(int)fminf(fmaxf(y1f, 0.0f), 511.0f); \
    uint32_t r0b = (yc0 << 11), r1b = (yc1 << 11); \
    float top = ldg_off(img, r0b + (xc0 << 2)) * wx0m + ldg_off(img, r0b + (xc1 << 2)) * wx1m; \
    float bot = ldg_off(img, r1b + (xc0 << 2)) * wx0m + ldg_off(img, r1b + (xc1 << 2)) * wx1m; \
    float val = top * wy0m + bot * wy1m; \
    acc0 += fabsf(val - ldg_off(ref, refoffB)); \
    hf += 1.0f; refoffB += 2048u; \
  } while (0)

  // branchless fast pixel: 2x dwordx2 corner pairs + 1 ref dword, ~19 VALU
#define FAST_PX(HF, ROFF, ACC) do { \
    float ix = fmaf(Bx, (HF), colx); \
    float iy = fmaf(By, (HF), coly); \
    float x0f = floorf(ix), y0f = floorf(iy); \
    float wx = ix - x0f, wy = iy - y0f; \
    uint32_t off = ((uint32_t)(int)y0f << 11) + ((uint32_t)(int)x0f << 2); \
    float2 vt = ldg2_off(img, off); \
    float2 vb = ldg2_off(img, off + 2048u); \
    float rr  = ldg_off(ref, (ROFF)); \
    float top = fmaf(wx, vt.y - vt.x, vt.x); \
    float bot = fmaf(wx, vb.y - vb.x, vb.x); \
    float val = fmaf(wy, bot - top, top); \
    ACC += fabsf(val - rr); \
  } while (0)

  for (int h = 0; h < lo; ++h) SLOW_PX;

  int h = lo;
#pragma unroll 1
  for (; h + 2 <= hi; h += 2) {
    FAST_PX(hf, refoffB, acc0);
    FAST_PX(hf + 1.0f, refoffB + 2048u, acc1);
    hf += 2.0f;
    refoffB += 4096u;
  }
  if (h < hi) {
    FAST_PX(hf, refoffB, acc0);
    hf += 1.0f;
    refoffB += 2048u;
  }

  for (int h2 = hi; h2 < ch; ++h2) SLOW_PX;
#undef SLOW_PX
#undef FAST_PX

  float acc = acc0 + acc1;
  if (tid >= cw) acc = 0.0f;

  // reduce: fp32 per-thread partials -> fp64 wave shuffle -> LDS -> thread 0
  double d = (double)acc;
  for (int off = 32; off; off >>= 1) d += __shfl_down(d, off);
  const int lane = tid & 63, wv = tid >> 6;
  if (lane == 0) wsum[wv] = d;
  __syncthreads();
  if (tid == 0) {
    double tot = 0.0;
    for (int i = 0; i < 8; ++i) tot += wsum[i];
    sad_out[combo * NBT + bt] = (float)(tot / (double)(ch * cw));
  }
}

// argmin over 225 combos per image + subpixel refinement (fp32, mirrors ref)
__global__ void argmin_kernel(const float* __restrict__ sad,
                              const float* __restrict__ shv,
                              const float* __restrict__ swv,
                              const float* __restrict__ rvv,
                              const float* __restrict__ scv,
                              float* __restrict__ out) {
  const int bt = threadIdx.x;
  if (bt >= NBT) return;
  float best = sad[bt];
  int bi = 0;
  for (int c = 1; c < NCOMBO; ++c) {
    float v = sad[c * NBT + bt];
    if (v < best) { best = v; bi = c; }  // strict < keeps first occurrence
  }
  int ihh = bi / (NW * NR * NS);
  int iww = (bi / (NR * NS)) % NW;
  int irr = (bi / NS) % NR;
  int iss = bi % NS;
  ihh = min(max(ihh, 1), NH - 2);
  iww = min(max(iww, 1), NW - 2);
  irr = min(max(irr, 1), NR - 2);
  iss = min(max(iss, 1), NS - 2);
  const int c0 = ihh * (NW * NR * NS) + iww * (NR * NS) + irr * NS + iss;
  const float y2 = sad[c0 * NBT + bt];

  const int strides[4] = { NW * NR * NS, NR * NS, NS, 1 };
  const float* vecs[4] = { shv, swv, rvv, scv };
  const int idxs[4] = { ihh, iww, irr, iss };
  for (int d = 0; d < 4; ++d) {
    float ya = sad[(c0 - strides[d]) * NBT + bt];
    float yc = sad[(c0 + strides[d]) * NBT + bt];
    float denom = ya - 2.0f * y2 + yc;
    denom = (fabsf(denom) < 1e-12f) ? 1e-12f : denom;
    float delta = 0.5f * (ya - yc) / denom;
    delta = fminf(fmaxf(delta, -1.0f), 1.0f);
    float step = vecs[d][1] - vecs[d][0];
    out[d * NBT + bt] = vecs[d][idxs[d]] + delta * step;
  }
}

extern "C" void kernel_launch(void* const* d_in, const int* in_sizes, int n_in,
                              void* d_out, int out_size, void* d_ws, size_t ws_size,
                              hipStream_t stream) {
  const float* matrix = (const float*)d_in[0];
  const float* refm   = (const float*)d_in[1];
  const float* shv    = (const float*)d_in[2];
  const float* swv    = (const float*)d_in[3];
  const float* rvv    = (const float*)d_in[4];
  const float* scv    = (const float*)d_in[5];
  float* out = (float*)d_out;
  float* sad = out + 4 * NBT;  // SAD chunk lives at offset 64 in d_out

  dim3 grid(NCOMBO, NBT);
  sad_kernel<<<grid, 512, 0, stream>>>(matrix, refm, shv, swv, rvv, scv, sad);
  argmin_kernel<<<1, 64, 0, stream>>>(sad, shv, swv, rvv, scv, out);
}

// Round 14
// 805.608 us; speedup vs baseline: 1.3145x; 1.3145x over previous
//
#include <hip/hip_runtime.h>

#ifndef M_PI
#define M_PI 3.14159265358979323846
#endif

#define HH 512
#define WW 512
#define NBT 16
#define NH 5
#define NW 5
#define NR 3
#define NS 3
#define NCOMBO (NH * NW * NR * NS)  // 225

struct BlockParams {
  float Ax, Bx, Cx, Ay, By, Cy;
  int ch, cw, y1, x1;
};

// load float at byte offset from uniform base -> global_load saddr + voffset
__device__ __forceinline__ float ldg_off(const float* base, uint32_t byteOff) {
  return *reinterpret_cast<const float*>(reinterpret_cast<const char*>(base) + byteOff);
}

// interval of t such that lo <= A*t + C <= hi
__device__ __forceinline__ void interval_1d(float A, float C, float lo, float hi,
                                            float& l, float& u) {
  if (fabsf(A) > 1e-7f) {
    float a = (lo - C) / A;
    float b = (hi - C) / A;
    l = fminf(a, b);
    u = fmaxf(a, b);
  } else {
    bool in = (C >= lo && C <= hi);
    l = in ? -1e9f : 1e9f;
    u = in ? 1e9f : -1e9f;
  }
}

// shared combo/crop parameter setup (thread 0 of each block)
__device__ __forceinline__ void setup_params(BlockParams& bp, int combo,
                                             const float* shv, const float* swv,
                                             const float* rvv, const float* scv) {
  // ---- crop sizes (mirrors _crop_sizes; fp64 for exact int truncation) ----
  double max_ash = 0.0, max_asw = 0.0, max_r = -1e300, max_s = -1e300;
  for (int i = 0; i < NH; ++i) max_ash = fmax(max_ash, fabs((double)shv[i]));
  for (int i = 0; i < NW; ++i) max_asw = fmax(max_asw, fabs((double)swv[i]));
  for (int i = 0; i < NR; ++i) {
    float rf = rvv[i] * (float)(M_PI / 180.0);  // fp32 like reference
    max_r = fmax(max_r, (double)rf);
  }
  for (int i = 0; i < NS; ++i) max_s = fmax(max_s, (double)scv[i]);
  double t = fabs(tan(max_r));
  int ch = (int)((double)HH - (2.0 * (max_ash + 0.5 * HH * t) * max_s + 10.0));
  int cw = (int)((double)WW - (2.0 * (max_asw + 0.5 * WW * t) * max_s + 10.0));
  bp.ch = ch; bp.cw = cw;
  bp.y1 = (HH - ch) / 2; bp.x1 = (WW - cw) / 2;

  // ---- affine: ix = Ax*wf + Bx*hf + Cx, iy = Ay*wf + By*hf + Cy ----
  int ihh = combo / (NW * NR * NS);
  int iww = (combo / (NR * NS)) % NW;
  int irr = (combo / NS) % NR;
  int iss = combo % NS;
  double s_h = (double)shv[ihh];
  double s_w = (double)swv[iww];
  float rotf = rvv[irr] * (float)(M_PI / 180.0);
  double rot = (double)rotf;
  double scl = (double)scv[iss];
  double cs = cos(rot), sn = sin(rot);
  double cWd = (WW - 1) * 0.5, cHd = (HH - 1) * 0.5;
  double kx = ((double)WW / (WW - 1)) / scl;
  double ky = ((double)HH / (HH - 1)) / scl;
  bp.Ax = (float)(cs * kx);
  bp.Bx = (float)(sn * kx);
  bp.Cx = (float)(kx * (cs * (s_w - cWd) + sn * (s_h - cHd)) + cWd);
  bp.Ay = (float)(-sn * ky);
  bp.By = (float)(cs * ky);
  bp.Cy = (float)(ky * (-sn * (s_w - cWd) + cs * (s_h - cHd)) + cHd);
}

// One block per (combo, image). 512 threads; thread = one crop column
// marching down crop rows. Fast path: VERTICAL REGISTER REUSE — y0
// advances +1 with x0 unchanged on ~93% of steps, so the top bilinear
// corners are the previous pixel's bottom corners (carried in registers).
// Rare invalid lanes take an exec-masked reload. 2 img loads + 1 ref
// load per pixel; ref load hoisted above the branch (no dependency).
__global__ __launch_bounds__(512)
void sad_kernel(const float* __restrict__ img_all,
                const float* __restrict__ ref_all,
                const float* __restrict__ shv, const float* __restrict__ swv,
                const float* __restrict__ rvv, const float* __restrict__ scv,
                float* __restrict__ sad_out) {
  __shared__ BlockParams bp;
  __shared__ double wsum[8];
  const int combo = blockIdx.x;
  const int bt = blockIdx.y;

  if (threadIdx.x == 0) setup_params(bp, combo, shv, swv, rvv, scv);
  __syncthreads();

  const int ch = bp.ch, cw = bp.cw, y1 = bp.y1, x1 = bp.x1;
  const float Ax = bp.Ax, Bx = bp.Bx, Cx = bp.Cx;
  const float Ay = bp.Ay, By = bp.By, Cy = bp.Cy;
  const float* __restrict__ img = img_all + (size_t)bt * (HH * WW);
  const float* __restrict__ ref = ref_all + (size_t)bt * (HH * WW);
  const int tid = threadIdx.x;

  const int wEff = (tid < cw) ? tid : (cw - 1);
  const float wfc = (float)(x1 + wEff);
  const float colx = fmaf(Ax, wfc, Cx);
  const float coly = fmaf(Ay, wfc, Cy);

  // fast-valid h interval: ix,iy in [0.01, 510.98] -> no masks, no clamps
  float lx, ux, ly, uy;
  interval_1d(Bx, colx, 0.01f, 510.98f, lx, ux);
  interval_1d(By, coly, 0.01f, 510.98f, ly, uy);
  float hl = fmaxf(lx, ly);
  float hu = fminf(ux, uy);
  hl = fmaxf(fminf(hl, 2000.0f), -2000.0f);
  hu = fmaxf(fminf(hu, 2000.0f), -2000.0f);
  int lo = (int)ceilf(hl) - y1;
  int hi = (int)floorf(hu) - y1 + 1;
  lo = min(max(lo, 0), ch);
  hi = min(max(hi, lo), ch);
  // wave-uniform intersection -> scalar loop bounds
  for (int off = 32; off; off >>= 1) {
    lo = max(lo, __shfl_xor(lo, off));
    hi = min(hi, __shfl_xor(hi, off));
  }
  hi = max(hi, lo);
  lo = __builtin_amdgcn_readfirstlane(lo);
  hi = __builtin_amdgcn_readfirstlane(hi);

  float acc0 = 0.0f, acc1 = 0.0f;
  float hf = (float)y1;
  uint32_t refoffB = (uint32_t)(y1 * WW + x1 + wEff) << 2;  // byte offset

#define SLOW_PX do { \
    float ix = fmaf(Bx, hf, colx); \
    float iy = fmaf(By, hf, coly); \
    float x0f = floorf(ix), y0f = floorf(iy); \
    float x1f = x0f + 1.0f, y1f = y0f + 1.0f; \
    float wx1 = ix - x0f, wy1 = iy - y0f; \
    float wx0 = 1.0f - wx1, wy0 = 1.0f - wy1; \
    float wx0m = (x0f >= 0.0f && x0f <= 511.0f) ? wx0 : 0.0f; \
    float wx1m = (x1f >= 0.0f && x1f <= 511.0f) ? wx1 : 0.0f; \
    float wy0m = (y0f >= 0.0f && y0f <= 511.0f) ? wy0 : 0.0f; \
    float wy1m = (y1f >= 0.0f && y1f <= 511.0f) ? wy1 : 0.0f; \
    uint32_t xc0 = (uint32_t)(int)fminf(fmaxf(x0f, 0.0f), 511.0f); \
    uint32_t xc1 = (uint32_t)(int)fminf(fmaxf(x1f, 0.0f), 511.0f); \
    uint32_t yc0 = (uint32_t)(int)fminf(fmaxf(y0f, 0.0f), 511.0f); \
    uint32_t yc1 = (uint32_t)(int)fminf(fmaxf(y1f, 0.0f), 511.0f); \
    uint32_t r0b = (yc0 << 11), r1b = (yc1 << 11); \
    float top = ldg_off(img, r0b + (xc0 << 2)) * wx0m + ldg_off(img, r0b + (xc1 << 2)) * wx1m; \
    float bot = ldg_off(img, r1b + (xc0 << 2)) * wx0m + ldg_off(img, r1b + (xc1 << 2)) * wx1m; \
    float val = top * wy0m + bot * wy1m; \
    acc0 += fabsf(val - ldg_off(ref, refoffB)); \
    hf += 1.0f; refoffB += 2048u; \
  } while (0)

  // vertical-reuse fast body: CIN = carried top corners, COUT = bottom
  // corners loaded here (become next row's CIN). offp/x0p/y0e carried.
  // rr load issued BEFORE the branch (independent of it).
#define VRB(HF, ROFF, ACC, CIN0, CIN1, COUT0, COUT1) do { \
    float ix = fmaf(Bx, (HF), colx); \
    float iy = fmaf(By, (HF), coly); \
    float rr = ldg_off(ref, (ROFF)); \
    float x0f = floorf(ix), y0f = floorf(iy); \
    float wx = ix - x0f, wy = iy - y0f; \
    uint32_t off = offp + 2048u; \
    if (!((x0f == x0p) && (y0f == y0e))) { \
      off = ((uint32_t)(int)y0f << 11) + ((uint32_t)(int)x0f << 2); \
      CIN0 = ldg_off(img, off); \
      CIN1 = ldg_off(img, off + 4u); \
    } \
    COUT0 = ldg_off(img, off + 2048u); \
    COUT1 = ldg_off(img, off + 2052u); \
    float top = fmaf(wx, CIN1 - CIN0, CIN0); \
    float bot = fmaf(wx, COUT1 - COUT0, COUT0); \
    float val = fmaf(wy, bot - top, top); \
    ACC += fabsf(val - rr); \
    offp = off; x0p = x0f; y0e = y0f + 1.0f; \
  } while (0)

  for (int h = 0; h < lo; ++h) SLOW_PX;

  {
    float cA0 = 0.0f, cA1 = 0.0f, cB0 = 0.0f, cB1 = 0.0f;
    float x0p = -3.0e8f, y0e = -3.0e8f;  // forces reload on first fast row
    uint32_t offp = 0;
    int h = lo;
    for (; h + 2 <= hi; h += 2) {
      VRB(hf,        refoffB,         acc0, cA0, cA1, cB0, cB1);
      VRB(hf + 1.0f, refoffB + 2048u, acc1, cB0, cB1, cA0, cA1);
      hf += 2.0f;
      refoffB += 4096u;
    }
    if (h < hi) {
      VRB(hf, refoffB, acc0, cA0, cA1, cB0, cB1);
      hf += 1.0f;
      refoffB += 2048u;
    }
  }

  for (int h2 = hi; h2 < ch; ++h2) SLOW_PX;
#undef SLOW_PX
#undef VRB

  float acc = acc0 + acc1;
  if (tid >= cw) acc = 0.0f;

  // reduce: fp32 per-thread partials -> fp64 wave shuffle -> LDS -> thread 0
  double d = (double)acc;
  for (int off = 32; off; off >>= 1) d += __shfl_down(d, off);
  const int lane = tid & 63, wv = tid >> 6;
  if (lane == 0) wsum[wv] = d;
  __syncthreads();
  if (tid == 0) {
    double tot = 0.0;
    for (int i = 0; i < 8; ++i) tot += wsum[i];
    sad_out[combo * NBT + bt] = (float)(tot / (double)(ch * cw));
  }
}

// argmin over 225 combos per image + subpixel refinement (fp32, mirrors ref)
__global__ void argmin_kernel(const float* __restrict__ sad,
                              const float* __restrict__ shv,
                              const float* __restrict__ swv,
                              const float* __restrict__ rvv,
                              const float* __restrict__ scv,
                              float* __restrict__ out) {
  const int bt = threadIdx.x;
  if (bt >= NBT) return;
  float best = sad[bt];
  int bi = 0;
  for (int c = 1; c < NCOMBO; ++c) {
    float v = sad[c * NBT + bt];
    if (v < best) { best = v; bi = c; }  // strict < keeps first occurrence
  }
  int ihh = bi / (NW * NR * NS);
  int iww = (bi / (NR * NS)) % NW;
  int irr = (bi / NS) % NR;
  int iss = bi % NS;
  ihh = min(max(ihh, 1), NH - 2);
  iww = min(max(iww, 1), NW - 2);
  irr = min(max(irr, 1), NR - 2);
  iss = min(max(iss, 1), NS - 2);
  const int c0 = ihh * (NW * NR * NS) + iww * (NR * NS) + irr * NS + iss;
  const float y2 = sad[c0 * NBT + bt];

  const int strides[4] = { NW * NR * NS, NR * NS, NS, 1 };
  const float* vecs[4] = { shv, swv, rvv, scv };
  const int idxs[4] = { ihh, iww, irr, iss };
  for (int d = 0; d < 4; ++d) {
    float ya = sad[(c0 - strides[d]) * NBT + bt];
    float yc = sad[(c0 + strides[d]) * NBT + bt];
    float denom = ya - 2.0f * y2 + yc;
    denom = (fabsf(denom) < 1e-12f) ? 1e-12f : denom;
    float delta = 0.5f * (ya - yc) / denom;
    delta = fminf(fmaxf(delta, -1.0f), 1.0f);
    float step = vecs[d][1] - vecs[d][0];
    out[d * NBT + bt] = vecs[d][idxs[d]] + delta * step;
  }
}

extern "C" void kernel_launch(void* const* d_in, const int* in_sizes, int n_in,
                              void* d_out, int out_size, void* d_ws, size_t ws_size,
                              hipStream_t stream) {
  const float* matrix = (const float*)d_in[0];
  const float* refm   = (const float*)d_in[1];
  const float* shv    = (const float*)d_in[2];
  const float* swv    = (const float*)d_in[3];
  const float* rvv    = (const float*)d_in[4];
  const float* scv    = (const float*)d_in[5];
  float* out = (float*)d_out;
  float* sad = out + 4 * NBT;  // SAD chunk lives at offset 64 in d_out

  dim3 grid(NCOMBO, NBT);
  sad_kernel<<<grid, 512, 0, stream>>>(matrix, refm, shv, swv, rvv, scv, sad);
  argmin_kernel<<<1, 64, 0, stream>>>(sad, shv, swv, rvv, scv, out);
}